// Round 4
// baseline (14540.611 us; speedup 1.0000x reference)
//
#include <hip/hip_runtime.h>

// ---------------- constants ----------------
#define H_    1024      // hidden = n_nodes
#define T_    128      // GRU input size
#define B_    32        // batch
#define S_    1024      // sequence length (node axis)
#define NB_   64        // persistent blocks
#define JB_   16        // hidden slice per block
#define KTOT_ 1152      // 1024 (h) + 128 (x)
#define KS_   36        // KTOT_/32 k-steps
#define NN_   (1024*1024)

typedef float f32x4 __attribute__((ext_vector_type(4)));
typedef __bf16 bf16x8 __attribute__((ext_vector_type(8)));

union FragU { uint4 q; bf16x8 v; unsigned short u[8]; };

static __device__ __forceinline__ unsigned short f2bf(float x) {
  unsigned u = __float_as_uint(x);
  u = (u + 0x7FFFu + ((u >> 16) & 1u)) >> 16;
  return (unsigned short)u;
}
static __device__ __forceinline__ float sigm(float x) { return 1.f / (1.f + __expf(-x)); }
static __device__ __forceinline__ float tanh_(float x) {
  float a = fabsf(x);
  float e = __expf(2.f * a);
  float t = 1.f - 2.f / (e + 1.f);
  return copysignf(t, x);
}
static __device__ __forceinline__ float lrelu(float x) { return x > 0.f ? x : 0.2f * x; }

static __device__ __forceinline__ void gld_lds16(const void* g, void* l) {
  __builtin_amdgcn_global_load_lds(
      (const __attribute__((address_space(1))) void*)g,
      (__attribute__((address_space(3))) void*)l, 16, 0, 0);
}

// ---------------- x transpose: [B,T,N] f32 -> xT [N][B][T] bf16 ----------------
__global__ __launch_bounds__(256) void k_transpose(const float* __restrict__ x,
                                                   unsigned short* __restrict__ xT) {
  __shared__ float tile[128][65];
  int b  = blockIdx.x >> 4;
  int n0 = (blockIdx.x & 15) * 64;
  int tid = threadIdx.x;
  int sub = tid >> 6, nn = tid & 63;
  for (int it = 0; it < 32; ++it) {
    int t = it * 4 + sub;
    tile[t][nn] = x[(size_t)(b * 128 + t) * 1024 + n0 + nn];
  }
  __syncthreads();
  int nl = tid >> 7, tt = tid & 127;
  for (int it = 0; it < 32; ++it) {
    int n = it * 2 + nl;
    xT[(size_t)(n0 + n) * 4096 + b * 128 + tt] = f2bf(tile[tt][n]);
  }
}

// ---------------- persistent GRU ----------------
// 64 blocks x 512 threads. Block bid owns hidden slice j0=bid*16.
// Weights held as MFMA B-fragments in registers; h broadcast via global (bf16).
__global__ __launch_bounds__(512) void k_gru(
    const float* __restrict__ w_ih, const float* __restrict__ w_hh,
    const float* __restrict__ b_ih, const float* __restrict__ b_hh,
    const float* __restrict__ wkey, const float* __restrict__ wqry,
    const unsigned short* __restrict__ xT,
    unsigned short* __restrict__ h_buf,   // [2][B_][H_] bf16
    int* __restrict__ done_blk,           // [NB_]
    float* __restrict__ key_v, float* __restrict__ qry_v)
{
  __shared__ uint4 h_lds4[B_][145];       // [32][1160 bf16] = h(1024) + x(128) + pad(8)
  __shared__ float gh_lds[B_][65];        // cols: r(0..15) z(16..31) nh(32..47) nx(48..63)
  __shared__ float wk_lds[S_], wq_lds[S_];

  const int tid  = threadIdx.x;
  const int bid  = blockIdx.x;
  const int lane = tid & 63;
  const int wave = tid >> 6;
  const int j0   = bid * JB_;

  for (int i = tid; i < S_; i += 512) { wk_lds[i] = wkey[i]; wq_lds[i] = wqry[i]; }

  // ---- one-time: load weight fragments into registers (waves 0..5) ----
  const int mtile = wave & 1;
  const int ntile = wave >> 1;
  bf16x8 wfrag[KS_];
  if (wave < 6) {
    int col = lane & 15, kg = lane >> 4;
    int grow = ntile * H_ + j0 + col;   // row in w_hh / w_ih (gate-major: r,z,n)
    for (int ks = 0; ks < KS_; ++ks) {
      int k = ks * 32 + kg * 8;
      const float* p = (k < H_) ? (w_hh + (size_t)grow * H_ + k)
                                : (w_ih + (size_t)grow * T_ + (k - H_));
      FragU cv;
      #pragma unroll
      for (int e = 0; e < 8; ++e) cv.u[e] = f2bf(p[e]);
      wfrag[ks] = cv.v;
    }
  }

  // epilogue mapping: thread -> (batch eb, local hidden ejl)
  const int ejl = tid & 15;
  const int eb  = tid >> 4;
  const float bs_r = b_ih[j0 + ejl]          + b_hh[j0 + ejl];
  const float bs_z = b_ih[H_ + j0 + ejl]     + b_hh[H_ + j0 + ejl];
  const float bn_i = b_ih[2 * H_ + j0 + ejl];
  const float bn_h = b_hh[2 * H_ + j0 + ejl];

  float hreg = 0.f;              // this thread's own h[eb][j0+ejl]
  float kacc = 0.f, qacc = 0.f;
  int spin_budget = 8000000;     // failsafe: terminate instead of hang

  for (int s = 0; s < S_; ++s) {
    if (s > 0) {
      if (wave == 0) {   // 64 lanes poll 64 per-block flags
        while (spin_budget > 0) {
          int v = __hip_atomic_load(&done_blk[lane], __ATOMIC_RELAXED, __HIP_MEMORY_SCOPE_AGENT);
          if (__all(v >= s)) break;
          __builtin_amdgcn_s_sleep(2);
          --spin_budget;
        }
      }
      __syncthreads();
      __threadfence();   // acquire: make other blocks' h stores visible (agent scope)
    }

    // ---- stage h^(s-1) (global bf16 -> LDS, async) ----
    const unsigned short* hprev = h_buf + ((s + 1) & 1) * (B_ * H_);
    #pragma unroll
    for (int r = 0; r < 4; ++r) {
      int b = wave * 4 + r;
      #pragma unroll
      for (int c = 0; c < 2; ++c)
        gld_lds16(hprev + b * H_ + c * 512 + lane * 8, &h_lds4[b][c * 64]);
    }
    // ---- stage x_s (reg path into padded rows) ----
    {
      const uint4* xT4 = (const uint4*)xT;
      h_lds4[eb][128 + ejl] = xT4[(size_t)s * 512 + eb * 16 + ejl];
    }
    __syncthreads();

    // ---- MFMA: gh[b, 48 gates] over K=1152 ----
    if (wave < 6) {
      const int ar = mtile * 16 + (lane & 15);
      const int kg = lane >> 4;
      if (ntile < 2) {            // r / z gates: single fused accumulator
        f32x4 a0 = {0.f,0.f,0.f,0.f}, a1 = {0.f,0.f,0.f,0.f};
        #pragma unroll
        for (int ks = 0; ks < KS_; ks += 2) {
          FragU fa, fb;
          fa.q = h_lds4[ar][(ks    ) * 4 + kg];
          fb.q = h_lds4[ar][(ks + 1) * 4 + kg];
          a0 = __builtin_amdgcn_mfma_f32_16x16x32_bf16(fa.v, wfrag[ks],     a0, 0, 0, 0);
          a1 = __builtin_amdgcn_mfma_f32_16x16x32_bf16(fb.v, wfrag[ks + 1], a1, 0, 0, 0);
        }
        f32x4 acc = a0 + a1;
        int dc = ntile * 16 + (lane & 15);
        int br = mtile * 16 + ((lane >> 4) << 2);
        #pragma unroll
        for (int r = 0; r < 4; ++r) gh_lds[br + r][dc] = acc[r];
      } else {                    // n gate: keep Whh*h and Wih*x separate
        f32x4 a0 = {0.f,0.f,0.f,0.f}, a1 = {0.f,0.f,0.f,0.f}, ax = {0.f,0.f,0.f,0.f};
        #pragma unroll
        for (int ks = 0; ks < 32; ks += 2) {
          FragU fa, fb;
          fa.q = h_lds4[ar][(ks    ) * 4 + kg];
          fb.q = h_lds4[ar][(ks + 1) * 4 + kg];
          a0 = __builtin_amdgcn_mfma_f32_16x16x32_bf16(fa.v, wfrag[ks],     a0, 0, 0, 0);
          a1 = __builtin_amdgcn_mfma_f32_16x16x32_bf16(fb.v, wfrag[ks + 1], a1, 0, 0, 0);
        }
        #pragma unroll
        for (int ks = 32; ks < 36; ++ks) {
          FragU fa;
          fa.q = h_lds4[ar][ks * 4 + kg];
          ax = __builtin_amdgcn_mfma_f32_16x16x32_bf16(fa.v, wfrag[ks], ax, 0, 0, 0);
        }
        f32x4 acc = a0 + a1;
        int cc = lane & 15;
        int br = mtile * 16 + ((lane >> 4) << 2);
        #pragma unroll
        for (int r = 0; r < 4; ++r) {
          gh_lds[br + r][32 + cc] = acc[r];
          gh_lds[br + r][48 + cc] = ax[r];
        }
      }
    }
    __syncthreads();

    // ---- gate epilogue (all 512 threads; one (b,j) each) ----
    {
      float rs = gh_lds[eb][ejl]      + bs_r;
      float zs = gh_lds[eb][16 + ejl] + bs_z;
      float nh = gh_lds[eb][32 + ejl] + bn_h;
      float nx = gh_lds[eb][48 + ejl] + bn_i;
      float r  = sigm(rs);
      float z  = sigm(zs);
      float n  = tanh_(nx + r * nh);
      float hn = (1.f - z) * n + z * hreg;
      hreg = hn;
      kacc += wk_lds[s] * hn;
      qacc += wq_lds[s] * hn;
      unsigned short* hcur = h_buf + (s & 1) * (B_ * H_);
      hcur[eb * H_ + j0 + ejl] = f2bf(hn);
    }
    __syncthreads();

    if (tid == 0) {
      __threadfence();   // release: flush h stores to agent-visible point
      __hip_atomic_store(&done_blk[bid], s + 1, __ATOMIC_RELEASE, __HIP_MEMORY_SCOPE_AGENT);
    }
  }

  key_v[eb * H_ + j0 + ejl] = kacc;
  qry_v[eb * H_ + j0 + ejl] = qacc;
}

// ---------------- qmax over j per batch ----------------
__global__ __launch_bounds__(256) void k_qmax(const float* __restrict__ qry_v,
                                              float* __restrict__ qmax) {
  int b = blockIdx.x, tid = threadIdx.x;
  float m = -1e30f;
  for (int i = tid; i < 1024; i += 256) m = fmaxf(m, qry_v[b * 1024 + i]);
  #pragma unroll
  for (int off = 32; off; off >>= 1) m = fmaxf(m, __shfl_xor(m, off));
  __shared__ float red[4];
  if ((tid & 63) == 0) red[tid >> 6] = m;
  __syncthreads();
  if (tid == 0) qmax[b] = fmaxf(fmaxf(red[0], red[1]), fmaxf(red[2], red[3]));
}

// ---------------- softmax denominators: one wave per (b,i) row ----------------
__global__ __launch_bounds__(256) void k_denom(const float* __restrict__ key_v,
                                               const float* __restrict__ qry_v,
                                               const float* __restrict__ qmax,
                                               float* __restrict__ mrow,
                                               float* __restrict__ rden) {
  int tid = threadIdx.x, lane = tid & 63;
  int row = blockIdx.x * 4 + (tid >> 6);           // b*1024+i
  int b = row >> 10;
  float k  = key_v[row];
  float mx = lrelu(k + qmax[b]);
  float sum = 0.f;
  for (int j = lane; j < 1024; j += 64)
    sum += __expf(lrelu(k + qry_v[b * 1024 + j]) - mx);
  #pragma unroll
  for (int off = 32; off; off >>= 1) sum += __shfl_xor(sum, off);
  if (lane == 0) { mrow[row] = mx; rden[row] = 1.f / sum; }
}

// ---------------- A_mean + degree ----------------
__global__ __launch_bounds__(256) void k_amean(const float* __restrict__ key_v,
                                               const float* __restrict__ qry_v,
                                               const float* __restrict__ mrow,
                                               const float* __restrict__ rden,
                                               float* __restrict__ A,
                                               float* __restrict__ degree) {
  __shared__ float qs[32][33];
  __shared__ float ks[32][9], ms[32][9], rs[32][9];
  int tid = threadIdx.x;
  int it = blockIdx.x >> 5, jt = blockIdx.x & 31;
  int i0 = it * 8, j0 = jt * 32;
  #pragma unroll
  for (int c = 0; c < 4; ++c) {
    int idx = tid + c * 256;
    int b = idx >> 5, j = idx & 31;
    qs[b][j] = qry_v[b * 1024 + j0 + j];
  }
  { int b = tid >> 3, ii = tid & 7;
    ks[b][ii] = key_v[b * 1024 + i0 + ii];
    ms[b][ii] = mrow[b * 1024 + i0 + ii];
    rs[b][ii] = rden[b * 1024 + i0 + ii]; }
  __syncthreads();
  int il = tid >> 5, jl = tid & 31;
  float acc = 0.f;
  #pragma unroll 4
  for (int b = 0; b < 32; ++b)
    acc += __expf(lrelu(ks[b][il] + qs[b][jl]) - ms[b][il]) * rs[b][il];
  acc *= (1.f / 32.f);
  A[(size_t)(i0 + il) * 1024 + j0 + jl] = acc;
  float v = acc;
  #pragma unroll
  for (int off = 16; off; off >>= 1) v += __shfl_xor(v, off);
  if (jl == 0) atomicAdd(&degree[i0 + il], v);
}

// ---------------- symmetrize + laplacian + attention output ----------------
__global__ __launch_bounds__(256) void k_lap(const float* __restrict__ A,
                                             const float* __restrict__ degree,
                                             float* __restrict__ lap,
                                             float* __restrict__ att) {
  __shared__ float ta[32][33], tb[32][33];
  int it = blockIdx.x >> 5, jt = blockIdx.x & 31;
  int i0 = it * 32, j0 = jt * 32;
  int tid = threadIdx.x;
  int r = tid >> 5, c = tid & 31;
  for (int rr = r; rr < 32; rr += 8) {
    ta[rr][c] = A[(size_t)(i0 + rr) * 1024 + j0 + c];
    tb[rr][c] = A[(size_t)(j0 + rr) * 1024 + i0 + c];
  }
  __syncthreads();
  for (int rr = r; rr < 32; rr += 8) {
    int i = i0 + rr, j = j0 + c;
    float asym = 0.5f * (ta[rr][c] + tb[c][rr]);
    float di = 1.f / (sqrtf(degree[i]) + 1e-7f);
    float dj = 1.f / (sqrtf(degree[j]) + 1e-7f);
    float lv = di * dj * (((i == j) ? degree[i] : 0.f) - asym);
    att[(size_t)i * 1024 + j] = asym;
    lap[(size_t)i * 1024 + j] = lv;
  }
}

// ---------------- fp32 tiled GEMM: C = alpha*A@B - sub ----------------
__global__ __launch_bounds__(256) void k_gemm(const float* __restrict__ A,
                                              const float* __restrict__ B,
                                              float* __restrict__ C, float alpha,
                                              const float* __restrict__ sub) {
  __shared__ float As[16][68], Bs[16][68];
  int it = blockIdx.x >> 4, jt = blockIdx.x & 15;
  int i0 = it * 64, j0 = jt * 64;
  int tid = threadIdx.x;
  float acc[4][4] = {};
  int rb = (tid >> 4) * 4, cb = (tid & 15) * 4;
  int arow = tid >> 2, akk = (tid & 3) * 4;
  int brow = tid >> 4, bjc = (tid & 15) * 4;
  for (int kt = 0; kt < 64; ++kt) {
    float4 av = *(const float4*)&A[(size_t)(i0 + arow) * 1024 + kt * 16 + akk];
    float4 bv = *(const float4*)&B[(size_t)(kt * 16 + brow) * 1024 + j0 + bjc];
    As[akk + 0][arow] = av.x; As[akk + 1][arow] = av.y;
    As[akk + 2][arow] = av.z; As[akk + 3][arow] = av.w;
    *(float4*)&Bs[brow][bjc] = bv;
    __syncthreads();
    #pragma unroll
    for (int k = 0; k < 16; ++k) {
      float4 a4 = *(const float4*)&As[k][rb];
      float4 b4 = *(const float4*)&Bs[k][cb];
      float aa[4] = {a4.x, a4.y, a4.z, a4.w};
      float bb[4] = {b4.x, b4.y, b4.z, b4.w};
      #pragma unroll
      for (int rr = 0; rr < 4; ++rr)
        #pragma unroll
        for (int cc = 0; cc < 4; ++cc) acc[rr][cc] += aa[rr] * bb[cc];
    }
    __syncthreads();
  }
  #pragma unroll
  for (int rr = 0; rr < 4; ++rr)
    #pragma unroll
    for (int cc = 0; cc < 4; ++cc) {
      size_t idx = (size_t)(i0 + rb + rr) * 1024 + j0 + cb + cc;
      float v = alpha * acc[rr][cc];
      if (sub) v -= sub[idx];
      C[idx] = v;
    }
}

// ---------------- launch ----------------
extern "C" void kernel_launch(void* const* d_in, const int* in_sizes, int n_in,
                              void* d_out, int out_size, void* d_ws, size_t ws_size,
                              hipStream_t stream) {
  const float* x    = (const float*)d_in[0];
  const float* w_ih = (const float*)d_in[1];
  const float* w_hh = (const float*)d_in[2];
  const float* b_ih = (const float*)d_in[3];
  const float* b_hh = (const float*)d_in[4];
  const float* wkey = (const float*)d_in[5];
  const float* wqry = (const float*)d_in[6];
  float* out = (float*)d_out;

  char* ws = (char*)d_ws;
  unsigned short* xT   = (unsigned short*)(ws);              // 8 MB
  unsigned short* hbuf = (unsigned short*)(ws + 8388608);    // 128 KB
  int*   done          = (int*)          (ws + 8519680);     // 4 KB
  float* key_v         = (float*)        (ws + 8523776);     // 128 KB
  float* qry_v         = (float*)        (ws + 8654848);     // 128 KB
  float* qmax          = (float*)        (ws + 8785920);     // 4 KB
  float* mrow          = (float*)        (ws + 8790016);     // 128 KB
  float* rden          = (float*)        (ws + 8921088);     // 128 KB
  float* degree        = (float*)        (ws + 9052160);     // 4 KB
  float* A             = (float*)        (ws + 9056256);     // 4 MB

  (void)hipMemsetAsync(hbuf, 0, 131072 + 4096, stream);   // h state + flags
  (void)hipMemsetAsync(degree, 0, 4096, stream);
  (void)hipMemsetAsync(out, 0, (size_t)NN_ * 4, stream);  // L0 = zeros

  k_transpose<<<512, 256, 0, stream>>>(x, xT);
  k_gru<<<NB_, 512, 0, stream>>>(w_ih, w_hh, b_ih, b_hh, wkey, wqry, xT, hbuf, done, key_v, qry_v);
  k_qmax<<<32, 256, 0, stream>>>(qry_v, qmax);
  k_denom<<<8192, 256, 0, stream>>>(key_v, qry_v, qmax, mrow, rden);
  k_amean<<<4096, 256, 0, stream>>>(key_v, qry_v, mrow, rden, A, degree);
  k_lap<<<1024, 256, 0, stream>>>(A, degree, out + NN_, out + (size_t)4 * NN_);
  k_gemm<<<256, 256, 0, stream>>>(out + NN_, out + NN_, out + (size_t)2 * NN_, 2.f, nullptr);
  k_gemm<<<256, 256, 0, stream>>>(out + NN_, out + (size_t)2 * NN_, out + (size_t)3 * NN_, 2.f, out + NN_);
}

// Round 5
// 5100.549 us; speedup vs baseline: 2.8508x; 2.8508x over previous
//
#include <hip/hip_runtime.h>

// ---------------- constants ----------------
#define H_    1024      // hidden = n_nodes
#define T_    128       // GRU input size
#define B_    32        // batch
#define S_    1024      // sequence length (node axis)
#define NB_   64        // persistent blocks
#define JB_   16        // hidden slice per block
#define KTOT_ 1152      // 1024 (h) + 128 (x)
#define KS_   36        // KTOT_/32 k-steps
#define NN_   (1024*1024)

typedef float f32x4 __attribute__((ext_vector_type(4)));
typedef __bf16 bf16x8 __attribute__((ext_vector_type(8)));

union FragU { uint4 q; bf16x8 v; unsigned short u[8]; };

static __device__ __forceinline__ unsigned short f2bf(float x) {
  unsigned u = __float_as_uint(x);
  u = (u + 0x7FFFu + ((u >> 16) & 1u)) >> 16;
  return (unsigned short)u;
}
static __device__ __forceinline__ float sigm(float x) { return 1.f / (1.f + __expf(-x)); }
static __device__ __forceinline__ float tanh_(float x) {
  float a = fabsf(x);
  float e = __expf(2.f * a);
  float t = 1.f - 2.f / (e + 1.f);
  return copysignf(t, x);
}
static __device__ __forceinline__ float lrelu(float x) { return x > 0.f ? x : 0.2f * x; }

// ---------------- x transpose: [B,T,N] f32 -> xT [N][B][T] bf16 ----------------
__global__ __launch_bounds__(256) void k_transpose(const float* __restrict__ x,
                                                   unsigned short* __restrict__ xT) {
  __shared__ float tile[128][65];
  int b  = blockIdx.x >> 4;
  int n0 = (blockIdx.x & 15) * 64;
  int tid = threadIdx.x;
  int sub = tid >> 6, nn = tid & 63;
  for (int it = 0; it < 32; ++it) {
    int t = it * 4 + sub;
    tile[t][nn] = x[(size_t)(b * 128 + t) * 1024 + n0 + nn];
  }
  __syncthreads();
  int nl = tid >> 7, tt = tid & 127;
  for (int it = 0; it < 32; ++it) {
    int n = it * 2 + nl;
    xT[(size_t)(n0 + n) * 4096 + b * 128 + tt] = f2bf(tile[tt][n]);
  }
}

// ---------------- persistent GRU ----------------
// 64 blocks x 512 threads. Block bid owns hidden slice j0=bid*16.
// h exchanged through LLC via relaxed agent-scope atomics (NO cache-
// maintenance fences — the round-4 14 µs/step was buffer_wbl2/inv per step).
__global__ __launch_bounds__(512) void k_gru(
    const float* __restrict__ w_ih, const float* __restrict__ w_hh,
    const float* __restrict__ b_ih, const float* __restrict__ b_hh,
    const float* __restrict__ wkey, const float* __restrict__ wqry,
    const unsigned short* __restrict__ xT,
    unsigned short* __restrict__ h_buf,   // [2][B_][H_] bf16
    int* __restrict__ done_blk,           // [NB_]
    float* __restrict__ key_v, float* __restrict__ qry_v)
{
  __shared__ uint4 h_lds4[B_][145];       // [32][1160 bf16] = h(1024) + x(128) + pad(8)
  __shared__ float gh_lds[B_][65];        // cols: r(0..15) z(16..31) nh(32..47) nx(48..63)
  __shared__ float wk_lds[S_], wq_lds[S_];

  const int tid  = threadIdx.x;
  const int bid  = blockIdx.x;
  const int lane = tid & 63;
  const int wave = tid >> 6;
  const int j0   = bid * JB_;

  for (int i = tid; i < S_; i += 512) { wk_lds[i] = wkey[i]; wq_lds[i] = wqry[i]; }

  // ---- one-time: load weight fragments into registers (waves 0..5) ----
  const int mtile = wave & 1;
  const int ntile = wave >> 1;
  bf16x8 wfrag[KS_];
  if (wave < 6) {
    int col = lane & 15, kg = lane >> 4;
    int grow = ntile * H_ + j0 + col;   // row in w_hh / w_ih (gate-major: r,z,n)
    for (int ks = 0; ks < KS_; ++ks) {
      int k = ks * 32 + kg * 8;
      const float* p = (k < H_) ? (w_hh + (size_t)grow * H_ + k)
                                : (w_ih + (size_t)grow * T_ + (k - H_));
      FragU cv;
      #pragma unroll
      for (int e = 0; e < 8; ++e) cv.u[e] = f2bf(p[e]);
      wfrag[ks] = cv.v;
    }
  }

  // epilogue mapping: thread -> (batch eb, local hidden ejl)
  const int ejl = tid & 15;
  const int eb  = tid >> 4;
  const float bs_r = b_ih[j0 + ejl]          + b_hh[j0 + ejl];
  const float bs_z = b_ih[H_ + j0 + ejl]     + b_hh[H_ + j0 + ejl];
  const float bn_i = b_ih[2 * H_ + j0 + ejl];
  const float bn_h = b_hh[2 * H_ + j0 + ejl];

  float hreg = 0.f;              // this thread's own h[eb][j0+ejl]
  float kacc = 0.f, qacc = 0.f;
  int spin_budget = 16000000;    // failsafe: terminate instead of hang

  for (int s = 0; s < S_; ++s) {
    if (s > 0) {
      if (wave == 0) {   // 64 lanes poll 64 per-block flags (LLC atomics)
        while (spin_budget > 0) {
          int v = __hip_atomic_load(&done_blk[lane], __ATOMIC_RELAXED, __HIP_MEMORY_SCOPE_AGENT);
          if (__all(v >= s)) break;
          __builtin_amdgcn_s_sleep(1);
          --spin_budget;
        }
      }
      __syncthreads();
      asm volatile("" ::: "memory");   // compiler barrier only — data path is LLC-coherent
    }

    // ---- stage h^(s-1): LLC atomic loads -> regs -> LDS (all 512 threads) ----
    {
      const unsigned short* hprev = h_buf + ((s + 1) & 1) * (B_ * H_);
      const unsigned long long* hp64 = (const unsigned long long*)hprev;  // 8192 chunks
      unsigned long long hv0, hv1, hv2, hv3, hv4, hv5, hv6, hv7;
      unsigned long long hv8, hv9, hvA, hvB, hvC, hvD, hvE, hvF;
      hv0 = __hip_atomic_load(hp64 +  0 * 512 + tid, __ATOMIC_RELAXED, __HIP_MEMORY_SCOPE_AGENT);
      hv1 = __hip_atomic_load(hp64 +  1 * 512 + tid, __ATOMIC_RELAXED, __HIP_MEMORY_SCOPE_AGENT);
      hv2 = __hip_atomic_load(hp64 +  2 * 512 + tid, __ATOMIC_RELAXED, __HIP_MEMORY_SCOPE_AGENT);
      hv3 = __hip_atomic_load(hp64 +  3 * 512 + tid, __ATOMIC_RELAXED, __HIP_MEMORY_SCOPE_AGENT);
      hv4 = __hip_atomic_load(hp64 +  4 * 512 + tid, __ATOMIC_RELAXED, __HIP_MEMORY_SCOPE_AGENT);
      hv5 = __hip_atomic_load(hp64 +  5 * 512 + tid, __ATOMIC_RELAXED, __HIP_MEMORY_SCOPE_AGENT);
      hv6 = __hip_atomic_load(hp64 +  6 * 512 + tid, __ATOMIC_RELAXED, __HIP_MEMORY_SCOPE_AGENT);
      hv7 = __hip_atomic_load(hp64 +  7 * 512 + tid, __ATOMIC_RELAXED, __HIP_MEMORY_SCOPE_AGENT);
      hv8 = __hip_atomic_load(hp64 +  8 * 512 + tid, __ATOMIC_RELAXED, __HIP_MEMORY_SCOPE_AGENT);
      hv9 = __hip_atomic_load(hp64 +  9 * 512 + tid, __ATOMIC_RELAXED, __HIP_MEMORY_SCOPE_AGENT);
      hvA = __hip_atomic_load(hp64 + 10 * 512 + tid, __ATOMIC_RELAXED, __HIP_MEMORY_SCOPE_AGENT);
      hvB = __hip_atomic_load(hp64 + 11 * 512 + tid, __ATOMIC_RELAXED, __HIP_MEMORY_SCOPE_AGENT);
      hvC = __hip_atomic_load(hp64 + 12 * 512 + tid, __ATOMIC_RELAXED, __HIP_MEMORY_SCOPE_AGENT);
      hvD = __hip_atomic_load(hp64 + 13 * 512 + tid, __ATOMIC_RELAXED, __HIP_MEMORY_SCOPE_AGENT);
      hvE = __hip_atomic_load(hp64 + 14 * 512 + tid, __ATOMIC_RELAXED, __HIP_MEMORY_SCOPE_AGENT);
      hvF = __hip_atomic_load(hp64 + 15 * 512 + tid, __ATOMIC_RELAXED, __HIP_MEMORY_SCOPE_AGENT);
      // x_s (plain L2-cached load — read-only input)
      uint4 xv = ((const uint4*)xT)[(size_t)s * 512 + eb * 16 + ejl];
      // LDS writes: chunk c = k*512+tid -> row b = 2k + (tid>>8), byte rem = (tid&255)*8
      char* hl = (char*)h_lds4;
      const int rsel = tid >> 8;          // 0/1
      const int rem  = (tid & 255) * 8;
      #define HSTORE(k, v) *(unsigned long long*)(hl + (2*(k) + rsel) * 2320 + rem) = (v)
      HSTORE(0, hv0);  HSTORE(1, hv1);  HSTORE(2, hv2);  HSTORE(3, hv3);
      HSTORE(4, hv4);  HSTORE(5, hv5);  HSTORE(6, hv6);  HSTORE(7, hv7);
      HSTORE(8, hv8);  HSTORE(9, hv9);  HSTORE(10, hvA); HSTORE(11, hvB);
      HSTORE(12, hvC); HSTORE(13, hvD); HSTORE(14, hvE); HSTORE(15, hvF);
      #undef HSTORE
      h_lds4[eb][128 + ejl] = xv;
    }
    __syncthreads();

    // ---- MFMA: gh[b, 48 gates] over K=1152 ----
    if (wave < 6) {
      const int ar = mtile * 16 + (lane & 15);
      const int kg = lane >> 4;
      if (ntile < 2) {            // r / z gates: single fused accumulator
        f32x4 a0 = {0.f,0.f,0.f,0.f}, a1 = {0.f,0.f,0.f,0.f};
        #pragma unroll
        for (int ks = 0; ks < KS_; ks += 2) {
          FragU fa, fb;
          fa.q = h_lds4[ar][(ks    ) * 4 + kg];
          fb.q = h_lds4[ar][(ks + 1) * 4 + kg];
          a0 = __builtin_amdgcn_mfma_f32_16x16x32_bf16(fa.v, wfrag[ks],     a0, 0, 0, 0);
          a1 = __builtin_amdgcn_mfma_f32_16x16x32_bf16(fb.v, wfrag[ks + 1], a1, 0, 0, 0);
        }
        f32x4 acc = a0 + a1;
        int dc = ntile * 16 + (lane & 15);
        int br = mtile * 16 + ((lane >> 4) << 2);
        #pragma unroll
        for (int r = 0; r < 4; ++r) gh_lds[br + r][dc] = acc[r];
      } else {                    // n gate: keep Whh*h and Wih*x separate
        f32x4 a0 = {0.f,0.f,0.f,0.f}, a1 = {0.f,0.f,0.f,0.f}, ax = {0.f,0.f,0.f,0.f};
        #pragma unroll
        for (int ks = 0; ks < 32; ks += 2) {
          FragU fa, fb;
          fa.q = h_lds4[ar][(ks    ) * 4 + kg];
          fb.q = h_lds4[ar][(ks + 1) * 4 + kg];
          a0 = __builtin_amdgcn_mfma_f32_16x16x32_bf16(fa.v, wfrag[ks],     a0, 0, 0, 0);
          a1 = __builtin_amdgcn_mfma_f32_16x16x32_bf16(fb.v, wfrag[ks + 1], a1, 0, 0, 0);
        }
        #pragma unroll
        for (int ks = 32; ks < 36; ++ks) {
          FragU fa;
          fa.q = h_lds4[ar][ks * 4 + kg];
          ax = __builtin_amdgcn_mfma_f32_16x16x32_bf16(fa.v, wfrag[ks], ax, 0, 0, 0);
        }
        f32x4 acc = a0 + a1;
        int cc = lane & 15;
        int br = mtile * 16 + ((lane >> 4) << 2);
        #pragma unroll
        for (int r = 0; r < 4; ++r) {
          gh_lds[br + r][32 + cc] = acc[r];
          gh_lds[br + r][48 + cc] = ax[r];
        }
      }
    }
    __syncthreads();

    // ---- gate epilogue (all 512 threads; one (b,j) each) ----
    {
      float rs = gh_lds[eb][ejl]      + bs_r;
      float zs = gh_lds[eb][16 + ejl] + bs_z;
      float nh = gh_lds[eb][32 + ejl] + bn_h;
      float nx = gh_lds[eb][48 + ejl] + bn_i;
      float r  = sigm(rs);
      float z  = sigm(zs);
      float n  = tanh_(nx + r * nh);
      float hn = (1.f - z) * n + z * hreg;
      hreg = hn;
      kacc += wk_lds[s] * hn;
      qacc += wq_lds[s] * hn;
      // pack 2 bf16 -> u32, store through LLC (agent-scope relaxed atomic)
      unsigned int hb = (unsigned int)f2bf(hn);
      unsigned int ob = __shfl_xor(hb, 1);
      if ((tid & 1) == 0) {
        unsigned short* hcur = h_buf + (s & 1) * (B_ * H_);
        unsigned int word = hb | (ob << 16);
        unsigned int* dst = (unsigned int*)(hcur + eb * H_ + j0 + ejl);
        __hip_atomic_store(dst, word, __ATOMIC_RELAXED, __HIP_MEMORY_SCOPE_AGENT);
      }
    }
    asm volatile("s_waitcnt vmcnt(0)" ::: "memory");  // h stores acked at LLC
    __syncthreads();                                   // all waves drained

    if (tid == 0)
      __hip_atomic_store(&done_blk[bid], s + 1, __ATOMIC_RELAXED, __HIP_MEMORY_SCOPE_AGENT);
  }

  key_v[eb * H_ + j0 + ejl] = kacc;
  qry_v[eb * H_ + j0 + ejl] = qacc;
}

// ---------------- qmax over j per batch ----------------
__global__ __launch_bounds__(256) void k_qmax(const float* __restrict__ qry_v,
                                              float* __restrict__ qmax) {
  int b = blockIdx.x, tid = threadIdx.x;
  float m = -1e30f;
  for (int i = tid; i < 1024; i += 256) m = fmaxf(m, qry_v[b * 1024 + i]);
  #pragma unroll
  for (int off = 32; off; off >>= 1) m = fmaxf(m, __shfl_xor(m, off));
  __shared__ float red[4];
  if ((tid & 63) == 0) red[tid >> 6] = m;
  __syncthreads();
  if (tid == 0) qmax[b] = fmaxf(fmaxf(red[0], red[1]), fmaxf(red[2], red[3]));
}

// ---------------- softmax denominators: one wave per (b,i) row ----------------
__global__ __launch_bounds__(256) void k_denom(const float* __restrict__ key_v,
                                               const float* __restrict__ qry_v,
                                               const float* __restrict__ qmax,
                                               float* __restrict__ mrow,
                                               float* __restrict__ rden) {
  int tid = threadIdx.x, lane = tid & 63;
  int row = blockIdx.x * 4 + (tid >> 6);           // b*1024+i
  int b = row >> 10;
  float k  = key_v[row];
  float mx = lrelu(k + qmax[b]);
  float sum = 0.f;
  for (int j = lane; j < 1024; j += 64)
    sum += __expf(lrelu(k + qry_v[b * 1024 + j]) - mx);
  #pragma unroll
  for (int off = 32; off; off >>= 1) sum += __shfl_xor(sum, off);
  if (lane == 0) { mrow[row] = mx; rden[row] = 1.f / sum; }
}

// ---------------- A_mean + degree ----------------
__global__ __launch_bounds__(256) void k_amean(const float* __restrict__ key_v,
                                               const float* __restrict__ qry_v,
                                               const float* __restrict__ mrow,
                                               const float* __restrict__ rden,
                                               float* __restrict__ A,
                                               float* __restrict__ degree) {
  __shared__ float qs[32][33];
  __shared__ float ks[32][9], ms[32][9], rs[32][9];
  int tid = threadIdx.x;
  int it = blockIdx.x >> 5, jt = blockIdx.x & 31;
  int i0 = it * 8, j0 = jt * 32;
  #pragma unroll
  for (int c = 0; c < 4; ++c) {
    int idx = tid + c * 256;
    int b = idx >> 5, j = idx & 31;
    qs[b][j] = qry_v[b * 1024 + j0 + j];
  }
  { int b = tid >> 3, ii = tid & 7;
    ks[b][ii] = key_v[b * 1024 + i0 + ii];
    ms[b][ii] = mrow[b * 1024 + i0 + ii];
    rs[b][ii] = rden[b * 1024 + i0 + ii]; }
  __syncthreads();
  int il = tid >> 5, jl = tid & 31;
  float acc = 0.f;
  #pragma unroll 4
  for (int b = 0; b < 32; ++b)
    acc += __expf(lrelu(ks[b][il] + qs[b][jl]) - ms[b][il]) * rs[b][il];
  acc *= (1.f / 32.f);
  A[(size_t)(i0 + il) * 1024 + j0 + jl] = acc;
  float v = acc;
  #pragma unroll
  for (int off = 16; off; off >>= 1) v += __shfl_xor(v, off);
  if (jl == 0) atomicAdd(&degree[i0 + il], v);
}

// ---------------- symmetrize + laplacian + attention output ----------------
__global__ __launch_bounds__(256) void k_lap(const float* __restrict__ A,
                                             const float* __restrict__ degree,
                                             float* __restrict__ lap,
                                             float* __restrict__ att) {
  __shared__ float ta[32][33], tb[32][33];
  int it = blockIdx.x >> 5, jt = blockIdx.x & 31;
  int i0 = it * 32, j0 = jt * 32;
  int tid = threadIdx.x;
  int r = tid >> 5, c = tid & 31;
  for (int rr = r; rr < 32; rr += 8) {
    ta[rr][c] = A[(size_t)(i0 + rr) * 1024 + j0 + c];
    tb[rr][c] = A[(size_t)(j0 + rr) * 1024 + i0 + c];
  }
  __syncthreads();
  for (int rr = r; rr < 32; rr += 8) {
    int i = i0 + rr, j = j0 + c;
    float asym = 0.5f * (ta[rr][c] + tb[c][rr]);
    float di = 1.f / (sqrtf(degree[i]) + 1e-7f);
    float dj = 1.f / (sqrtf(degree[j]) + 1e-7f);
    float lv = di * dj * (((i == j) ? degree[i] : 0.f) - asym);
    att[(size_t)i * 1024 + j] = asym;
    lap[(size_t)i * 1024 + j] = lv;
  }
}

// ---------------- fp32 tiled GEMM: C = alpha*A@B - sub ----------------
__global__ __launch_bounds__(256) void k_gemm(const float* __restrict__ A,
                                              const float* __restrict__ B,
                                              float* __restrict__ C, float alpha,
                                              const float* __restrict__ sub) {
  __shared__ float As[16][68], Bs[16][68];
  int it = blockIdx.x >> 4, jt = blockIdx.x & 15;
  int i0 = it * 64, j0 = jt * 64;
  int tid = threadIdx.x;
  float acc[4][4] = {};
  int rb = (tid >> 4) * 4, cb = (tid & 15) * 4;
  int arow = tid >> 2, akk = (tid & 3) * 4;
  int brow = tid >> 4, bjc = (tid & 15) * 4;
  for (int kt = 0; kt < 64; ++kt) {
    float4 av = *(const float4*)&A[(size_t)(i0 + arow) * 1024 + kt * 16 + akk];
    float4 bv = *(const float4*)&B[(size_t)(kt * 16 + brow) * 1024 + j0 + bjc];
    As[akk + 0][arow] = av.x; As[akk + 1][arow] = av.y;
    As[akk + 2][arow] = av.z; As[akk + 3][arow] = av.w;
    *(float4*)&Bs[brow][bjc] = bv;
    __syncthreads();
    #pragma unroll
    for (int k = 0; k < 16; ++k) {
      float4 a4 = *(const float4*)&As[k][rb];
      float4 b4 = *(const float4*)&Bs[k][cb];
      float aa[4] = {a4.x, a4.y, a4.z, a4.w};
      float bb[4] = {b4.x, b4.y, b4.z, b4.w};
      #pragma unroll
      for (int rr = 0; rr < 4; ++rr)
        #pragma unroll
        for (int cc = 0; cc < 4; ++cc) acc[rr][cc] += aa[rr] * bb[cc];
    }
    __syncthreads();
  }
  #pragma unroll
  for (int rr = 0; rr < 4; ++rr)
    #pragma unroll
    for (int cc = 0; cc < 4; ++cc) {
      size_t idx = (size_t)(i0 + rb + rr) * 1024 + j0 + cb + cc;
      float v = alpha * acc[rr][cc];
      if (sub) v -= sub[idx];
      C[idx] = v;
    }
}

// ---------------- launch ----------------
extern "C" void kernel_launch(void* const* d_in, const int* in_sizes, int n_in,
                              void* d_out, int out_size, void* d_ws, size_t ws_size,
                              hipStream_t stream) {
  const float* x    = (const float*)d_in[0];
  const float* w_ih = (const float*)d_in[1];
  const float* w_hh = (const float*)d_in[2];
  const float* b_ih = (const float*)d_in[3];
  const float* b_hh = (const float*)d_in[4];
  const float* wkey = (const float*)d_in[5];
  const float* wqry = (const float*)d_in[6];
  float* out = (float*)d_out;

  char* ws = (char*)d_ws;
  unsigned short* xT   = (unsigned short*)(ws);              // 8 MB
  unsigned short* hbuf = (unsigned short*)(ws + 8388608);    // 128 KB
  int*   done          = (int*)          (ws + 8519680);     // 4 KB
  float* key_v         = (float*)        (ws + 8523776);     // 128 KB
  float* qry_v         = (float*)        (ws + 8654848);     // 128 KB
  float* qmax          = (float*)        (ws + 8785920);     // 4 KB
  float* mrow          = (float*)        (ws + 8790016);     // 128 KB
  float* rden          = (float*)        (ws + 8921088);     // 128 KB
  float* degree        = (float*)        (ws + 9052160);     // 4 KB
  float* A             = (float*)        (ws + 9056256);     // 4 MB

  (void)hipMemsetAsync(hbuf, 0, 131072 + 4096, stream);   // h state + flags
  (void)hipMemsetAsync(degree, 0, 4096, stream);
  (void)hipMemsetAsync(out, 0, (size_t)NN_ * 4, stream);  // L0 = zeros

  k_transpose<<<512, 256, 0, stream>>>(x, xT);
  k_gru<<<NB_, 512, 0, stream>>>(w_ih, w_hh, b_ih, b_hh, wkey, wqry, xT, hbuf, done, key_v, qry_v);
  k_qmax<<<32, 256, 0, stream>>>(qry_v, qmax);
  k_denom<<<8192, 256, 0, stream>>>(key_v, qry_v, qmax, mrow, rden);
  k_amean<<<4096, 256, 0, stream>>>(key_v, qry_v, mrow, rden, A, degree);
  k_lap<<<1024, 256, 0, stream>>>(A, degree, out + NN_, out + (size_t)4 * NN_);
  k_gemm<<<256, 256, 0, stream>>>(out + NN_, out + NN_, out + (size_t)2 * NN_, 2.f, nullptr);
  k_gemm<<<256, 256, 0, stream>>>(out + NN_, out + (size_t)2 * NN_, out + (size_t)3 * NN_, 2.f, out + NN_);
}

// Round 6
// 4910.849 us; speedup vs baseline: 2.9609x; 1.0386x over previous
//
#include <hip/hip_runtime.h>

// ---------------- constants ----------------
#define H_    1024      // hidden = n_nodes
#define T_    128       // GRU input size
#define B_    32        // batch
#define S_    1024      // sequence length (node axis)
#define NB_   64        // persistent blocks
#define JB_   16        // hidden slice per block
#define KS_   36        // K-steps of 32 over 1024(h)+128(x)
#define NN_   (1024*1024)

typedef float f32x4 __attribute__((ext_vector_type(4)));
typedef __bf16 bf16x8 __attribute__((ext_vector_type(8)));

union FragU { uint4 q; bf16x8 v; unsigned short u[8]; };

static __device__ __forceinline__ unsigned short f2bf(float x) {
  unsigned u = __float_as_uint(x);
  u = (u + 0x7FFFu + ((u >> 16) & 1u)) >> 16;
  return (unsigned short)u;
}
static __device__ __forceinline__ float sigm(float x) { return 1.f / (1.f + __expf(-x)); }
static __device__ __forceinline__ float tanh_(float x) {
  float a = fabsf(x);
  float e = __expf(2.f * a);
  float t = 1.f - 2.f / (e + 1.f);
  return copysignf(t, x);
}
static __device__ __forceinline__ float lrelu(float x) { return x > 0.f ? x : 0.2f * x; }

// cached async global->LDS (read-only inputs)
static __device__ __forceinline__ void gld_lds16_c(const void* g, void* l) {
  __builtin_amdgcn_global_load_lds(
      (const __attribute__((address_space(1))) void*)g,
      (__attribute__((address_space(3))) void*)l, 16, 0, 0);
}
// device-coherent async global->LDS: CPol SC0|SC1 = 1|16 -> bypass L1/L2, read at LLC
static __device__ __forceinline__ void gld_lds16_cc(const void* g, void* l) {
  __builtin_amdgcn_global_load_lds(
      (const __attribute__((address_space(1))) void*)g,
      (__attribute__((address_space(3))) void*)l, 16, 0, 17);
}

// ---------------- x transpose: [B,T,N] f32 -> xT slice-major [N][q=T/16][B][16] bf16 ----------------
__global__ __launch_bounds__(256) void k_transpose(const float* __restrict__ x,
                                                   unsigned short* __restrict__ xT) {
  __shared__ float tile[128][65];
  int b  = blockIdx.x >> 4;
  int n0 = (blockIdx.x & 15) * 64;
  int tid = threadIdx.x;
  int sub = tid >> 6, nn = tid & 63;
  for (int it = 0; it < 32; ++it) {
    int t = it * 4 + sub;
    tile[t][nn] = x[(size_t)(b * 128 + t) * 1024 + n0 + nn];
  }
  __syncthreads();
  int nl = tid >> 7, tt = tid & 127;
  for (int it = 0; it < 32; ++it) {
    int n = it * 2 + nl;
    xT[(size_t)(n0 + n) * 4096 + (tt >> 4) * 512 + b * 16 + (tt & 15)] = f2bf(tile[tt][n]);
  }
}

// ---------------- persistent GRU ----------------
// 64 blocks x 512 threads. Block bid owns gate-col slice j0=bid*16.
// h state is slice-major in global: h_buf[2][64 slices][512] bf16 (1KB/slice).
// Producers: relaxed agent-scope atomic stores (land at LLC).
// Consumers: per-producer flag gating + global_load_lds (SC0|SC1) -> LDS, async.
__global__ __launch_bounds__(512) void k_gru(
    const float* __restrict__ w_ih, const float* __restrict__ w_hh,
    const float* __restrict__ b_ih, const float* __restrict__ b_hh,
    const float* __restrict__ wkey, const float* __restrict__ wqry,
    const unsigned short* __restrict__ xT,
    unsigned short* __restrict__ h_buf,   // [2][NB_][512] bf16 slice-major
    int* __restrict__ done_blk,           // [NB_]
    float* __restrict__ key_v, float* __restrict__ qry_v)
{
  __shared__ unsigned short h_sm[72][520];  // slices 0..63 = h, 64..71 = x; 512 data + 8 pad
  __shared__ float gh_lds[B_][65];          // cols: r(0..15) z(16..31) nh(32..47) nx(48..63)
  __shared__ float wk_lds[S_], wq_lds[S_];

  const int tid  = threadIdx.x;
  const int bid  = blockIdx.x;
  const int lane = tid & 63;
  const int wave = tid >> 6;
  const int j0   = bid * JB_;

  for (int i = tid; i < S_; i += 512) { wk_lds[i] = wkey[i]; wq_lds[i] = wqry[i]; }

  // ---- one-time: load weight fragments into registers (waves 0..5) ----
  const int mtile = wave & 1;
  const int ntile = wave >> 1;
  bf16x8 wfrag[KS_];
  if (wave < 6) {
    int col = lane & 15, kg = lane >> 4;
    int grow = ntile * H_ + j0 + col;   // row in w_hh / w_ih (gate-major: r,z,n)
    for (int ks = 0; ks < KS_; ++ks) {
      int k = ks * 32 + kg * 8;
      const float* p = (k < H_) ? (w_hh + (size_t)grow * H_ + k)
                                : (w_ih + (size_t)grow * T_ + (k - H_));
      FragU cv;
      #pragma unroll
      for (int e = 0; e < 8; ++e) cv.u[e] = f2bf(p[e]);
      wfrag[ks] = cv.v;
    }
  }

  // epilogue mapping: thread -> (batch eb, local hidden ejl); tid == eb*16+ejl
  const int ejl = tid & 15;
  const int eb  = tid >> 4;
  const float bs_r = b_ih[j0 + ejl]          + b_hh[j0 + ejl];
  const float bs_z = b_ih[H_ + j0 + ejl]     + b_hh[H_ + j0 + ejl];
  const float bn_i = b_ih[2 * H_ + j0 + ejl];
  const float bn_h = b_hh[2 * H_ + j0 + ejl];

  float hreg = 0.f;              // this thread's own h[eb][j0+ejl]
  float kacc = 0.f, qacc = 0.f;
  int spin_budget = 16000000;    // failsafe: terminate instead of hang

  const int pbase = wave * 8;            // this wave's 8 producer slices
  const int fl    = pbase + (lane & 7);  // flag index this lane mirrors

  for (int s = 0; s < S_; ++s) {
    const unsigned short* hprev = h_buf + ((s + 1) & 1) * (NB_ * 512);

    // ---- x slice for this wave (always ready; cached path), async ----
    gld_lds16_c(xT + (size_t)s * 4096 + wave * 512 + lane * 8, &h_sm[64 + wave][0]);

    // ---- per-producer gated h staging: issue slice load as soon as its flag lands ----
    {
      unsigned pend = 0xFFu;
      while (pend) {
        int v = __hip_atomic_load(&done_blk[fl], __ATOMIC_RELAXED, __HIP_MEMORY_SCOPE_AGENT);
        unsigned r8 = (unsigned)__ballot(v >= s) & pend & 0xFFu;
        while (r8) {
          int i = __ffs(r8) - 1; r8 &= r8 - 1; pend &= ~(1u << i);
          int p = pbase + i;
          gld_lds16_cc(hprev + p * 512 + lane * 8, &h_sm[p][0]);
        }
        if (pend) {
          __builtin_amdgcn_s_sleep(1);
          if (--spin_budget < 0) pend = 0;   // failsafe
        }
      }
    }
    asm volatile("s_waitcnt vmcnt(0)" ::: "memory");  // all staged loads landed in LDS
    __syncthreads();

    // ---- MFMA: gh[b, 48 gates] over K=1152 (slice-major A-frags) ----
    if (wave < 6) {
      const int abase = (mtile * 16 + (lane & 15)) * 16 + ((lane >> 4) & 1) * 8;
      const int ksl   = lane >> 5;           // (kg>>1): slice sub-select
      if (ntile < 2) {            // r / z gates: single fused accumulator
        f32x4 a0 = {0.f,0.f,0.f,0.f}, a1 = {0.f,0.f,0.f,0.f};
        #pragma unroll
        for (int ks = 0; ks < KS_; ks += 2) {
          FragU fa, fb;
          fa.q = *(const uint4*)&h_sm[2 * ks       + ksl][abase];
          fb.q = *(const uint4*)&h_sm[2 * (ks + 1) + ksl][abase];
          a0 = __builtin_amdgcn_mfma_f32_16x16x32_bf16(fa.v, wfrag[ks],     a0, 0, 0, 0);
          a1 = __builtin_amdgcn_mfma_f32_16x16x32_bf16(fb.v, wfrag[ks + 1], a1, 0, 0, 0);
        }
        f32x4 acc = a0 + a1;
        int dc = ntile * 16 + (lane & 15);
        int br = mtile * 16 + ((lane >> 4) << 2);
        #pragma unroll
        for (int r = 0; r < 4; ++r) gh_lds[br + r][dc] = acc[r];
      } else {                    // n gate: keep Whh*h and Wih*x separate
        f32x4 a0 = {0.f,0.f,0.f,0.f}, a1 = {0.f,0.f,0.f,0.f}, ax = {0.f,0.f,0.f,0.f};
        #pragma unroll
        for (int ks = 0; ks < 32; ks += 2) {
          FragU fa, fb;
          fa.q = *(const uint4*)&h_sm[2 * ks       + ksl][abase];
          fb.q = *(const uint4*)&h_sm[2 * (ks + 1) + ksl][abase];
          a0 = __builtin_amdgcn_mfma_f32_16x16x32_bf16(fa.v, wfrag[ks],     a0, 0, 0, 0);
          a1 = __builtin_amdgcn_mfma_f32_16x16x32_bf16(fb.v, wfrag[ks + 1], a1, 0, 0, 0);
        }
        #pragma unroll
        for (int ks = 32; ks < 36; ++ks) {
          FragU fa;
          fa.q = *(const uint4*)&h_sm[2 * ks + ksl][abase];
          ax = __builtin_amdgcn_mfma_f32_16x16x32_bf16(fa.v, wfrag[ks], ax, 0, 0, 0);
        }
        f32x4 acc = a0 + a1;
        int cc = lane & 15;
        int br = mtile * 16 + ((lane >> 4) << 2);
        #pragma unroll
        for (int r = 0; r < 4; ++r) {
          gh_lds[br + r][32 + cc] = acc[r];
          gh_lds[br + r][48 + cc] = ax[r];
        }
      }
    }
    __syncthreads();

    // ---- gate epilogue (all 512 threads; one (b,j) each) ----
    {
      float rs = gh_lds[eb][ejl]      + bs_r;
      float zs = gh_lds[eb][16 + ejl] + bs_z;
      float nh = gh_lds[eb][32 + ejl] + bn_h;
      float nx = gh_lds[eb][48 + ejl] + bn_i;
      float r  = sigm(rs);
      float z  = sigm(zs);
      float n  = tanh_(nx + r * nh);
      float hn = (1.f - z) * n + z * hreg;
      hreg = hn;
      kacc += wk_lds[s] * hn;
      qacc += wq_lds[s] * hn;
      // pack 2 bf16 -> u32, store slice-major through LLC (agent-scope relaxed atomic)
      unsigned int hb = (unsigned int)f2bf(hn);
      unsigned int ob = __shfl_xor(hb, 1);
      if ((tid & 1) == 0) {
        unsigned short* hcur = h_buf + (s & 1) * (NB_ * 512);
        unsigned int word = hb | (ob << 16);
        unsigned int* dst = (unsigned int*)(hcur + bid * 512 + tid);
        __hip_atomic_store(dst, word, __ATOMIC_RELAXED, __HIP_MEMORY_SCOPE_AGENT);
      }
    }
    asm volatile("s_waitcnt vmcnt(0)" ::: "memory");  // h stores acked at LLC
    __syncthreads();                                   // all waves drained

    if (tid == 0)
      __hip_atomic_store(&done_blk[bid], s + 1, __ATOMIC_RELAXED, __HIP_MEMORY_SCOPE_AGENT);
  }

  key_v[eb * H_ + j0 + ejl] = kacc;
  qry_v[eb * H_ + j0 + ejl] = qacc;
}

// ---------------- qmax over j per batch ----------------
__global__ __launch_bounds__(256) void k_qmax(const float* __restrict__ qry_v,
                                              float* __restrict__ qmax) {
  int b = blockIdx.x, tid = threadIdx.x;
  float m = -1e30f;
  for (int i = tid; i < 1024; i += 256) m = fmaxf(m, qry_v[b * 1024 + i]);
  #pragma unroll
  for (int off = 32; off; off >>= 1) m = fmaxf(m, __shfl_xor(m, off));
  __shared__ float red[4];
  if ((tid & 63) == 0) red[tid >> 6] = m;
  __syncthreads();
  if (tid == 0) qmax[b] = fmaxf(fmaxf(red[0], red[1]), fmaxf(red[2], red[3]));
}

// ---------------- softmax denominators: one wave per (b,i) row ----------------
__global__ __launch_bounds__(256) void k_denom(const float* __restrict__ key_v,
                                               const float* __restrict__ qry_v,
                                               const float* __restrict__ qmax,
                                               float* __restrict__ mrow,
                                               float* __restrict__ rden) {
  int tid = threadIdx.x, lane = tid & 63;
  int row = blockIdx.x * 4 + (tid >> 6);           // b*1024+i
  int b = row >> 10;
  float k  = key_v[row];
  float mx = lrelu(k + qmax[b]);
  float sum = 0.f;
  for (int j = lane; j < 1024; j += 64)
    sum += __expf(lrelu(k + qry_v[b * 1024 + j]) - mx);
  #pragma unroll
  for (int off = 32; off; off >>= 1) sum += __shfl_xor(sum, off);
  if (lane == 0) { mrow[row] = mx; rden[row] = 1.f / sum; }
}

// ---------------- A_mean + degree ----------------
__global__ __launch_bounds__(256) void k_amean(const float* __restrict__ key_v,
                                               const float* __restrict__ qry_v,
                                               const float* __restrict__ mrow,
                                               const float* __restrict__ rden,
                                               float* __restrict__ A,
                                               float* __restrict__ degree) {
  __shared__ float qs[32][33];
  __shared__ float ks[32][9], ms[32][9], rs[32][9];
  int tid = threadIdx.x;
  int it = blockIdx.x >> 5, jt = blockIdx.x & 31;
  int i0 = it * 8, j0 = jt * 32;
  #pragma unroll
  for (int c = 0; c < 4; ++c) {
    int idx = tid + c * 256;
    int b = idx >> 5, j = idx & 31;
    qs[b][j] = qry_v[b * 1024 + j0 + j];
  }
  { int b = tid >> 3, ii = tid & 7;
    ks[b][ii] = key_v[b * 1024 + i0 + ii];
    ms[b][ii] = mrow[b * 1024 + i0 + ii];
    rs[b][ii] = rden[b * 1024 + i0 + ii]; }
  __syncthreads();
  int il = tid >> 5, jl = tid & 31;
  float acc = 0.f;
  #pragma unroll 4
  for (int b = 0; b < 32; ++b)
    acc += __expf(lrelu(ks[b][il] + qs[b][jl]) - ms[b][il]) * rs[b][il];
  acc *= (1.f / 32.f);
  A[(size_t)(i0 + il) * 1024 + j0 + jl] = acc;
  float v = acc;
  #pragma unroll
  for (int off = 16; off; off >>= 1) v += __shfl_xor(v, off);
  if (jl == 0) atomicAdd(&degree[i0 + il], v);
}

// ---------------- symmetrize + laplacian + attention output ----------------
__global__ __launch_bounds__(256) void k_lap(const float* __restrict__ A,
                                             const float* __restrict__ degree,
                                             float* __restrict__ lap,
                                             float* __restrict__ att) {
  __shared__ float ta[32][33], tb[32][33];
  int it = blockIdx.x >> 5, jt = blockIdx.x & 31;
  int i0 = it * 32, j0 = jt * 32;
  int tid = threadIdx.x;
  int r = tid >> 5, c = tid & 31;
  for (int rr = r; rr < 32; rr += 8) {
    ta[rr][c] = A[(size_t)(i0 + rr) * 1024 + j0 + c];
    tb[rr][c] = A[(size_t)(j0 + rr) * 1024 + i0 + c];
  }
  __syncthreads();
  for (int rr = r; rr < 32; rr += 8) {
    int i = i0 + rr, j = j0 + c;
    float asym = 0.5f * (ta[rr][c] + tb[c][rr]);
    float di = 1.f / (sqrtf(degree[i]) + 1e-7f);
    float dj = 1.f / (sqrtf(degree[j]) + 1e-7f);
    float lv = di * dj * (((i == j) ? degree[i] : 0.f) - asym);
    att[(size_t)i * 1024 + j] = asym;
    lap[(size_t)i * 1024 + j] = lv;
  }
}

// ---------------- fp32 tiled GEMM: C = alpha*A@B - sub ----------------
__global__ __launch_bounds__(256) void k_gemm(const float* __restrict__ A,
                                              const float* __restrict__ B,
                                              float* __restrict__ C, float alpha,
                                              const float* __restrict__ sub) {
  __shared__ float As[16][68], Bs[16][68];
  int it = blockIdx.x >> 4, jt = blockIdx.x & 15;
  int i0 = it * 64, j0 = jt * 64;
  int tid = threadIdx.x;
  float acc[4][4] = {};
  int rb = (tid >> 4) * 4, cb = (tid & 15) * 4;
  int arow = tid >> 2, akk = (tid & 3) * 4;
  int brow = tid >> 4, bjc = (tid & 15) * 4;
  for (int kt = 0; kt < 64; ++kt) {
    float4 av = *(const float4*)&A[(size_t)(i0 + arow) * 1024 + kt * 16 + akk];
    float4 bv = *(const float4*)&B[(size_t)(kt * 16 + brow) * 1024 + j0 + bjc];
    As[akk + 0][arow] = av.x; As[akk + 1][arow] = av.y;
    As[akk + 2][arow] = av.z; As[akk + 3][arow] = av.w;
    *(float4*)&Bs[brow][bjc] = bv;
    __syncthreads();
    #pragma unroll
    for (int k = 0; k < 16; ++k) {
      float4 a4 = *(const float4*)&As[k][rb];
      float4 b4 = *(const float4*)&Bs[k][cb];
      float aa[4] = {a4.x, a4.y, a4.z, a4.w};
      float bb[4] = {b4.x, b4.y, b4.z, b4.w};
      #pragma unroll
      for (int rr = 0; rr < 4; ++rr)
        #pragma unroll
        for (int cc = 0; cc < 4; ++cc) acc[rr][cc] += aa[rr] * bb[cc];
    }
    __syncthreads();
  }
  #pragma unroll
  for (int rr = 0; rr < 4; ++rr)
    #pragma unroll
    for (int cc = 0; cc < 4; ++cc) {
      size_t idx = (size_t)(i0 + rb + rr) * 1024 + j0 + cb + cc;
      float v = alpha * acc[rr][cc];
      if (sub) v -= sub[idx];
      C[idx] = v;
    }
}

// ---------------- launch ----------------
extern "C" void kernel_launch(void* const* d_in, const int* in_sizes, int n_in,
                              void* d_out, int out_size, void* d_ws, size_t ws_size,
                              hipStream_t stream) {
  const float* x    = (const float*)d_in[0];
  const float* w_ih = (const float*)d_in[1];
  const float* w_hh = (const float*)d_in[2];
  const float* b_ih = (const float*)d_in[3];
  const float* b_hh = (const float*)d_in[4];
  const float* wkey = (const float*)d_in[5];
  const float* wqry = (const float*)d_in[6];
  float* out = (float*)d_out;

  char* ws = (char*)d_ws;
  unsigned short* xT   = (unsigned short*)(ws);              // 8 MB
  unsigned short* hbuf = (unsigned short*)(ws + 8388608);    // 128 KB
  int*   done          = (int*)          (ws + 8519680);     // 4 KB
  float* key_v         = (float*)        (ws + 8523776);     // 128 KB
  float* qry_v         = (float*)        (ws + 8654848);     // 128 KB
  float* qmax          = (float*)        (ws + 8785920);     // 4 KB
  float* mrow          = (float*)        (ws + 8790016);     // 128 KB
  float* rden          = (float*)        (ws + 8921088);     // 128 KB
  float* degree        = (float*)        (ws + 9052160);     // 4 KB
  float* A             = (float*)        (ws + 9056256);     // 4 MB

  (void)hipMemsetAsync(hbuf, 0, 131072 + 4096, stream);   // h state + flags
  (void)hipMemsetAsync(degree, 0, 4096, stream);
  (void)hipMemsetAsync(out, 0, (size_t)NN_ * 4, stream);  // L0 = zeros

  k_transpose<<<512, 256, 0, stream>>>(x, xT);
  k_gru<<<NB_, 512, 0, stream>>>(w_ih, w_hh, b_ih, b_hh, wkey, wqry, xT, hbuf, done, key_v, qry_v);
  k_qmax<<<32, 256, 0, stream>>>(qry_v, qmax);
  k_denom<<<8192, 256, 0, stream>>>(key_v, qry_v, qmax, mrow, rden);
  k_amean<<<4096, 256, 0, stream>>>(key_v, qry_v, mrow, rden, A, degree);
  k_lap<<<1024, 256, 0, stream>>>(A, degree, out + NN_, out + (size_t)4 * NN_);
  k_gemm<<<256, 256, 0, stream>>>(out + NN_, out + NN_, out + (size_t)2 * NN_, 2.f, nullptr);
  k_gemm<<<256, 256, 0, stream>>>(out + NN_, out + (size_t)2 * NN_, out + (size_t)3 * NN_, 2.f, out + NN_);
}